// Round 3
// baseline (16.358 us; speedup 1.0000x reference)
//
#include <hip/hip_runtime.h>

// CaptionEmbedder: out[b,l,:] = select-by-mask gather of a 512-float row.
//   VOCAB=32000, N_ENT=64, N_FACT=512, D=512, B=128, L=128
//   mask==1 -> entities_encoded[b, clamp(ci - VOCAB, ->N_ENT-1)]
//   mask==2 -> facts_encoded[b, clamp(ci - VOCAB - N_ENT, ->N_FACT-1)]
//   else    -> word_embedding[ci >= VOCAB ? pad : ci]
// Pure memory-bound gather: ~32 MB write + ~11-32 MB read.

constexpr int VOCAB  = 32000;
constexpr int N_ENT  = 64;
constexpr int N_FACT = 512;
constexpr int D      = 512;
constexpr int L      = 128;

typedef float f32x4 __attribute__((ext_vector_type(4)));  // native vec: ok for nontemporal builtins

constexpr int TPR   = 64;          // one wave per row
constexpr int BLOCK = 256;         // 4 rows per block

__global__ __launch_bounds__(BLOCK) void caption_embed_kernel(
    const int*   __restrict__ idx,     // [B*L]
    const f32x4* __restrict__ ents,    // [B, N_ENT, D/4]
    const f32x4* __restrict__ facts,   // [B, N_FACT, D/4]
    const f32x4* __restrict__ words,   // [VOCAB, D/4]
    const int*   __restrict__ pad_tok, // [1]
    const int*   __restrict__ masks,   // [B*L]
    f32x4*       __restrict__ out)     // [B*L, D/4]
{
    const int tid = blockIdx.x * BLOCK + threadIdx.x;
    // 64 threads (one wave) per row -> row is wave-uniform; force scalar.
    const int row = __builtin_amdgcn_readfirstlane(tid >> 6);
    const int col = threadIdx.x & 63;   // float4 index 0..63 (and +64)

    const int b  = row >> 7;            // row / L
    const int ci = idx[row];            // uniform address -> s_load
    const int m  = masks[row];          // uniform address -> s_load

    const f32x4* src;
    int src_row;
    if (m == 1) {
        int e = ci - VOCAB;
        if (e < 0 || e >= N_ENT) e = N_ENT - 1;
        src = ents + (long)b * (N_ENT * (D / 4));
        src_row = e;
    } else if (m == 2) {
        int f = ci - VOCAB - N_ENT;
        if (f < 0 || f >= N_FACT) f = N_FACT - 1;
        src = facts + (long)b * (N_FACT * (D / 4));
        src_row = f;
    } else {
        int w = (ci >= VOCAB) ? pad_tok[0] : ci;
        src = words;
        src_row = w;
    }

    const f32x4* s = src + (long)src_row * (D / 4) + col;
    f32x4*       d = out + (long)row * (D / 4) + col;

    f32x4 v0 = s[0];
    f32x4 v1 = s[64];
    __builtin_nontemporal_store(v0, d);
    __builtin_nontemporal_store(v1, d + 64);
}

extern "C" void kernel_launch(void* const* d_in, const int* in_sizes, int n_in,
                              void* d_out, int out_size, void* d_ws, size_t ws_size,
                              hipStream_t stream) {
    const int*   idx     = (const int*)d_in[0];
    const f32x4* ents    = (const f32x4*)d_in[1];
    const f32x4* facts   = (const f32x4*)d_in[2];
    const f32x4* words   = (const f32x4*)d_in[3];
    const int*   pad_tok = (const int*)d_in[4];
    const int*   masks   = (const int*)d_in[5];
    f32x4*       out     = (f32x4*)d_out;

    const int n_rows = in_sizes[0];          // B*L = 16384
    const int grid   = n_rows * TPR / BLOCK; // 4096 blocks

    caption_embed_kernel<<<grid, BLOCK, 0, stream>>>(
        idx, ents, facts, words, pad_tok, masks, out);
}

// Round 4
// 12.001 us; speedup vs baseline: 1.3630x; 1.3630x over previous
//
#include <hip/hip_runtime.h>

// CaptionEmbedder: out[b,l,:] = select-by-mask gather of a 512-float row.
//   VOCAB=32000, N_ENT=64, N_FACT=512, D=512, B=128, L=128
//   mask==1 -> entities_encoded[b, clamp(ci - VOCAB, ->N_ENT-1)]
//   mask==2 -> facts_encoded[b, clamp(ci - VOCAB - N_ENT, ->N_FACT-1)]
//   else    -> word_embedding[ci >= VOCAB ? pad : ci]
// Pure memory-bound gather. R1 structure (13.9us) + nontemporal stores only.

constexpr int VOCAB  = 32000;
constexpr int N_ENT  = 64;
constexpr int N_FACT = 512;
constexpr int D      = 512;
constexpr int L      = 128;

typedef float f32x4 __attribute__((ext_vector_type(4)));

constexpr int TPR   = D / 4;   // 128 threads per row, 1 float4 each
constexpr int BLOCK = 256;     // 2 rows per block

__global__ __launch_bounds__(BLOCK) void caption_embed_kernel(
    const int*   __restrict__ idx,     // [B*L]
    const f32x4* __restrict__ ents,    // [B, N_ENT, D/4]
    const f32x4* __restrict__ facts,   // [B, N_FACT, D/4]
    const f32x4* __restrict__ words,   // [VOCAB, D/4]
    const int*   __restrict__ pad_tok, // [1]
    const int*   __restrict__ masks,   // [B*L]
    f32x4*       __restrict__ out,     // [B*L, D/4]
    int n_rows)
{
    const int tid = blockIdx.x * BLOCK + threadIdx.x;
    const int row = tid / TPR;
    const int col = tid % TPR;
    if (row >= n_rows) return;

    const int b  = row / L;
    const int ci = idx[row];
    const int m  = masks[row];

    const f32x4* src;
    long src_row;
    if (m == 1) {
        int e = ci - VOCAB;
        if (e < 0 || e >= N_ENT) e = N_ENT - 1;
        src = ents;
        src_row = (long)b * N_ENT + e;
    } else if (m == 2) {
        int f = ci - VOCAB - N_ENT;
        if (f < 0 || f >= N_FACT) f = N_FACT - 1;
        src = facts;
        src_row = (long)b * N_FACT + f;
    } else {
        int w = (ci >= VOCAB) ? pad_tok[0] : ci;
        src = words;
        src_row = w;
    }

    f32x4 v = src[src_row * TPR + col];
    __builtin_nontemporal_store(v, &out[(long)row * TPR + col]);
}

extern "C" void kernel_launch(void* const* d_in, const int* in_sizes, int n_in,
                              void* d_out, int out_size, void* d_ws, size_t ws_size,
                              hipStream_t stream) {
    const int*   idx     = (const int*)d_in[0];
    const f32x4* ents    = (const f32x4*)d_in[1];
    const f32x4* facts   = (const f32x4*)d_in[2];
    const f32x4* words   = (const f32x4*)d_in[3];
    const int*   pad_tok = (const int*)d_in[4];
    const int*   masks   = (const int*)d_in[5];
    f32x4*       out     = (f32x4*)d_out;

    const int n_rows = in_sizes[0];             // B*L = 16384
    const int total  = n_rows * TPR;
    const int grid   = (total + BLOCK - 1) / BLOCK;  // 8192

    caption_embed_kernel<<<grid, BLOCK, 0, stream>>>(
        idx, ents, facts, words, pad_tok, masks, out, n_rows);
}

// Round 5
// 11.675 us; speedup vs baseline: 1.4011x; 1.0280x over previous
//
#include <hip/hip_runtime.h>

// CaptionEmbedder: out[b,l,:] = select-by-mask gather of a 512-float row.
//   VOCAB=32000, N_ENT=64, N_FACT=512, D=512, B=128, L=128
//   mask==1 -> entities_encoded[b, clamp(ci - VOCAB, ->N_ENT-1)]
//   mask==2 -> facts_encoded[b, clamp(ci - VOCAB - N_ENT, ->N_FACT-1)]
//   else    -> word_embedding[ci >= VOCAB ? pad : ci]
// R4 (12.0us): thread-per-float4 + NT stores. R5: 2 independent rows per
// thread -> 2x memory-level parallelism for the latency-bound gather.

constexpr int VOCAB  = 32000;
constexpr int N_ENT  = 64;
constexpr int N_FACT = 512;
constexpr int D      = 512;
constexpr int L      = 128;

typedef float f32x4 __attribute__((ext_vector_type(4)));

constexpr int TPR   = D / 4;   // 128 threads per row, 1 float4 each
constexpr int BLOCK = 256;

__device__ __forceinline__ const f32x4* row_src(
    int ci, int m, int b, int pad,
    const f32x4* __restrict__ ents,
    const f32x4* __restrict__ facts,
    const f32x4* __restrict__ words)
{
    if (m == 1) {
        int e = ci - VOCAB;
        if (e < 0 || e >= N_ENT) e = N_ENT - 1;
        return ents + ((long)b * N_ENT + e) * TPR;
    } else if (m == 2) {
        int f = ci - VOCAB - N_ENT;
        if (f < 0 || f >= N_FACT) f = N_FACT - 1;
        return facts + ((long)b * N_FACT + f) * TPR;
    } else {
        int w = (ci >= VOCAB) ? pad : ci;
        return words + (long)w * TPR;
    }
}

__global__ __launch_bounds__(BLOCK) void caption_embed_kernel(
    const int*   __restrict__ idx,     // [B*L]
    const f32x4* __restrict__ ents,    // [B, N_ENT, D/4]
    const f32x4* __restrict__ facts,   // [B, N_FACT, D/4]
    const f32x4* __restrict__ words,   // [VOCAB, D/4]
    const int*   __restrict__ pad_tok, // [1]
    const int*   __restrict__ masks,   // [B*L]
    f32x4*       __restrict__ out,     // [B*L, D/4]
    int half_rows)                     // n_rows / 2
{
    const int tid  = blockIdx.x * BLOCK + threadIdx.x;
    const int row0 = tid / TPR;        // 0 .. half_rows-1
    const int col  = tid % TPR;
    if (row0 >= half_rows) return;
    const int row1 = row0 + half_rows;

    const int pad = pad_tok[0];

    const int ci0 = idx[row0];
    const int m0  = masks[row0];
    const int ci1 = idx[row1];
    const int m1  = masks[row1];

    const f32x4* s0 = row_src(ci0, m0, row0 / L, pad, ents, facts, words);
    const f32x4* s1 = row_src(ci1, m1, row1 / L, pad, ents, facts, words);

    // issue both gathers before consuming either -> 2x MLP
    f32x4 v0 = s0[col];
    f32x4 v1 = s1[col];

    __builtin_nontemporal_store(v0, &out[(long)row0 * TPR + col]);
    __builtin_nontemporal_store(v1, &out[(long)row1 * TPR + col]);
}

extern "C" void kernel_launch(void* const* d_in, const int* in_sizes, int n_in,
                              void* d_out, int out_size, void* d_ws, size_t ws_size,
                              hipStream_t stream) {
    const int*   idx     = (const int*)d_in[0];
    const f32x4* ents    = (const f32x4*)d_in[1];
    const f32x4* facts   = (const f32x4*)d_in[2];
    const f32x4* words   = (const f32x4*)d_in[3];
    const int*   pad_tok = (const int*)d_in[4];
    const int*   masks   = (const int*)d_in[5];
    f32x4*       out     = (f32x4*)d_out;

    const int n_rows    = in_sizes[0];          // B*L = 16384
    const int half_rows = n_rows / 2;
    const int total     = half_rows * TPR;
    const int grid      = (total + BLOCK - 1) / BLOCK;  // 4096

    caption_embed_kernel<<<grid, BLOCK, 0, stream>>>(
        idx, ents, facts, words, pad_tok, masks, out, half_rows);
}